// Round 1
// 253.041 us; speedup vs baseline: 1.0134x; 1.0134x over previous
//
#include <hip/hip_runtime.h>

// WaveletParsingLayer: per-row stable stream compaction.
// x3[B,C,L] -> out[B,C,KEEP], dropping elements == FILLER (10.1f), order-preserving.
// x1, x2 are unused by the reference.
//
// R5: R4's counters show the kernel itself is < 78 us (doesn't make rocprof
// top-5; harness 512MB fills @ 86% HBM peak dominate the profile). Roofline
// for the op is ~37 us, so the kernel-side residual is exposed latency:
// 49.4 KB LDS -> 3 blocks/CU, and at BLOCK=256 that is only 12 waves/CU
// (37.5%). Fix: BLOCK=512 (8 waves) -> same 3 blocks/CU but 24 waves/CU
// (75%), halved per-thread serial work, and the 4-element pos++ dependency
// chain replaced with independent ballot-bit offsets.

#define FILLER_VAL 10.1f
constexpr int L_LEN    = 16384;
constexpr int KEEP_LEN = 12288;
constexpr int BLOCK    = 512;           // 8 waves of 64
constexpr int NW       = BLOCK / 64;    // waves per block = 8
constexpr int CHUNK    = BLOCK * 4;     // 2048 elements per chunk
constexpr int NC       = L_LEN / CHUNK; // 8 chunks per row

__global__ __launch_bounds__(BLOCK, 6) void compact_rows_kernel(
    const float* __restrict__ x3, float* __restrict__ out)
{
    const int row = blockIdx.x;
    const float* __restrict__ in = x3 + (size_t)row * L_LEN;
    float* __restrict__ o = out + (size_t)row * KEEP_LEN;

    const int tid  = threadIdx.x;
    const int lane = tid & 63;
    const int wid  = tid >> 6;
    const unsigned long long lt = (1ULL << lane) - 1ULL;

    __shared__ float stage[KEEP_LEN];   // 48 KB survivor staging
    __shared__ int wtot[NC][NW];        // per-chunk per-wave survivor counts

    // ---- Load entire row (8 float4/thread, independent loads).
    float4 v[NC];
    #pragma unroll
    for (int c = 0; c < NC; ++c)
        v[c] = *reinterpret_cast<const float4*>(in + c * CHUNK + tid * 4);

    // ---- Ballot counts. Element order: idx = c*2048 + wid*256 + lane*4 + j.
    int before[NC];
    int b0[NC], b1[NC], b2[NC];         // this lane's survivor bits (j=0..2)
    #pragma unroll
    for (int c = 0; c < NC; ++c) {
        unsigned long long m0 = __ballot(v[c].x != FILLER_VAL);
        unsigned long long m1 = __ballot(v[c].y != FILLER_VAL);
        unsigned long long m2 = __ballot(v[c].z != FILLER_VAL);
        unsigned long long m3 = __ballot(v[c].w != FILLER_VAL);
        before[c] = __popcll(m0 & lt) + __popcll(m1 & lt)
                  + __popcll(m2 & lt) + __popcll(m3 & lt);
        b0[c] = (int)((m0 >> lane) & 1ULL);
        b1[c] = (int)((m1 >> lane) & 1ULL);
        b2[c] = (int)((m2 >> lane) & 1ULL);
        if (lane == 0)
            wtot[c][wid] = __popcll(m0) + __popcll(m1)
                         + __popcll(m2) + __popcll(m3);
    }
    __syncthreads();   // barrier 1: wtot visible

    // ---- Prefix over (chunk, wave) + scatter survivors into LDS stage.
    // Positions are independent per element (no serial pos++ chain).
    int run = 0;
    #pragma unroll
    for (int c = 0; c < NC; ++c) {
        int wb = run;
        #pragma unroll
        for (int w = 0; w < NW; ++w) {
            int t = wtot[c][w];
            if (w < wid) wb += t;
            run += t;
        }
        const int p0 = wb + before[c];
        const int p1 = p0 + b0[c];
        const int p2 = p1 + b1[c];
        const int p3 = p2 + b2[c];
        if (v[c].x != FILLER_VAL && p0 < KEEP_LEN) stage[p0] = v[c].x;
        if (v[c].y != FILLER_VAL && p1 < KEEP_LEN) stage[p1] = v[c].y;
        if (v[c].z != FILLER_VAL && p2 < KEEP_LEN) stage[p2] = v[c].z;
        if (v[c].w != FILLER_VAL && p3 < KEEP_LEN) stage[p3] = v[c].w;
    }
    __syncthreads();   // barrier 2: stage complete

    // ---- Coalesced copy-out: 12288 floats = 6 float4 per thread.
    #pragma unroll
    for (int k = 0; k < KEEP_LEN / (BLOCK * 4); ++k) {
        const int idx = (k * BLOCK + tid) * 4;
        float4 val = *reinterpret_cast<const float4*>(&stage[idx]);
        *reinterpret_cast<float4*>(&o[idx]) = val;
    }
}

extern "C" void kernel_launch(void* const* d_in, const int* in_sizes, int n_in,
                              void* d_out, int out_size, void* d_ws, size_t ws_size,
                              hipStream_t stream)
{
    // in order: x1 [B,C,4096] f32 (unused), x2 [B,C,4096] f32 (unused),
    //           x3 [B,C,L] f32, keep_len (scalar int, value 12288)
    const float* x3 = (const float*)d_in[2];
    float* out = (float*)d_out;

    const int rows = in_sizes[2] / L_LEN;  // B*C = 2048

    compact_rows_kernel<<<rows, BLOCK, 0, stream>>>(x3, out);
}